// Round 1
// baseline (409.921 us; speedup 1.0000x reference)
//
#include <hip/hip_runtime.h>
#include <hip/hip_bf16.h>
#include <stdint.h>

#define SEQ 4096
#define HID 1152
#define NH  16
#define HD  72
#define HDP 96   // head dim padded for QK^T K-dim (multiple of 32)
#define HDV 80   // head dim padded for PV N-dim (multiple of 16)
#define N3  3456

typedef __bf16 bf16;
typedef __bf16 bf16x8 __attribute__((ext_vector_type(8)));
typedef float  f32x4  __attribute__((ext_vector_type(4)));

__device__ __forceinline__ void gload_lds16(const void* g, void* l) {
    __builtin_amdgcn_global_load_lds(
        (__attribute__((address_space(1))) void*)(void*)g,
        (__attribute__((address_space(3))) void*)l, 16, 0, 0);
}

// ---------------- elementwise f32 -> bf16 (8/thread) ----------------
__global__ void cvt_bf16(const float* __restrict__ in, bf16* __restrict__ out, int n8)
{
    int i = blockIdx.x * 256 + threadIdx.x;
    if (i >= n8) return;
    const float4* p = (const float4*)in + (size_t)i * 2;
    float4 a = p[0], b = p[1];
    bf16x8 o;
    o[0]=(bf16)a.x; o[1]=(bf16)a.y; o[2]=(bf16)a.z; o[3]=(bf16)a.w;
    o[4]=(bf16)b.x; o[5]=(bf16)b.y; o[6]=(bf16)b.z; o[7]=(bf16)b.w;
    ((bf16x8*)out)[i] = o;
}

// ---------------- [R][C] f32 -> [C][R] bf16 (tiled transpose) ----------------
__global__ void transpose_cvt(const float* __restrict__ in, bf16* __restrict__ out, int R, int C)
{
    __shared__ float tl[32][33];
    int c0 = blockIdx.x * 32, r0 = blockIdx.y * 32;
    int tx = threadIdx.x & 31, ty = threadIdx.x >> 5;   // ty: 0..7
#pragma unroll
    for (int i = 0; i < 4; ++i)
        tl[ty + 8*i][tx] = in[(size_t)(r0 + ty + 8*i) * C + c0 + tx];
    __syncthreads();
#pragma unroll
    for (int i = 0; i < 4; ++i)
        out[(size_t)(c0 + ty + 8*i) * R + r0 + tx] = (bf16)tl[tx][ty + 8*i];
}

// ---------------- GEMM: C[M][N] = A[M][K] * BT[N][K]^T + bias ----------------
// m97 structure: 128x128 tile, BK=32, 4 waves each 64x64, global_load_lds w16.
template<int OUT_F32>
__global__ __launch_bounds__(256)
void gemm_bt(const bf16* __restrict__ A, const bf16* __restrict__ BT,
             const float* __restrict__ bias, void* __restrict__ out,
             int M, int N, int K)
{
    __shared__ __align__(16) bf16 As[128 * 32];
    __shared__ __align__(16) bf16 Bs[128 * 32];
    int tid = threadIdx.x;
    int lane = tid & 63, w = tid >> 6;
    int wm = w & 1, wn = w >> 1;
    int m0 = blockIdx.x * 128, n0 = blockIdx.y * 128;
    int lq = lane & 15, lk = lane >> 4;

    f32x4 acc[4][4] = {};

    for (int k0 = 0; k0 < K; k0 += 32) {
        __syncthreads();
#pragma unroll
        for (int i = 0; i < 2; ++i) {
            int c = w * 128 + i * 64 + lane;                 // chunk id 0..511
            const bf16* ga = A  + (size_t)(m0 + (c >> 2)) * K + k0 + (c & 3) * 8;
            const bf16* gb = BT + (size_t)(n0 + (c >> 2)) * K + k0 + (c & 3) * 8;
            gload_lds16(ga, (char*)As + (w * 128 + i * 64) * 16);
            gload_lds16(gb, (char*)Bs + (w * 128 + i * 64) * 16);
        }
        __syncthreads();
        bf16x8 af[4], bfr[4];
#pragma unroll
        for (int m = 0; m < 4; ++m)
            af[m] = *(const bf16x8*)&As[(wm * 64 + m * 16 + lq) * 32 + lk * 8];
#pragma unroll
        for (int n = 0; n < 4; ++n)
            bfr[n] = *(const bf16x8*)&Bs[(wn * 64 + n * 16 + lq) * 32 + lk * 8];
#pragma unroll
        for (int m = 0; m < 4; ++m)
#pragma unroll
            for (int n = 0; n < 4; ++n)
                acc[m][n] = __builtin_amdgcn_mfma_f32_16x16x32_bf16(af[m], bfr[n], acc[m][n], 0, 0, 0);
    }

    int rb = m0 + wm * 64, cb = n0 + wn * 64;
#pragma unroll
    for (int m = 0; m < 4; ++m) {
#pragma unroll
        for (int n = 0; n < 4; ++n) {
            int col = cb + n * 16 + lq;
            float b = bias[col];
#pragma unroll
            for (int r = 0; r < 4; ++r) {
                int row = rb + m * 16 + lk * 4 + r;
                float v = acc[m][n][r] + b;
                if (OUT_F32) ((float*)out)[(size_t)row * N + col] = v;
                else         ((bf16*)out)[(size_t)row * N + col] = (bf16)v;
            }
        }
    }
}

// ---------------- RoPE + pack Q,K into [h][seq][96] (zero-padded) ----------------
__global__ void rope_pack_qk(const bf16* __restrict__ qkv, const float* __restrict__ cs,
                             const float* __restrict__ sn, bf16* __restrict__ Qp,
                             bf16* __restrict__ Kp)
{
    int idx = blockIdx.x * 256 + threadIdx.x;   // over SEQ*NH*HDP
    int d  = idx % HDP;
    int t  = idx / HDP;
    int hh = t % NH;
    int s  = t / NH;
    size_t off = ((size_t)hh * SEQ + s) * HDP + d;
    if (d >= HD) { Qp[off] = (bf16)0.f; Kp[off] = (bf16)0.f; return; }
    float c  = cs[s * HD + d];
    float si = sn[s * HD + d];
    const bf16* row = qkv + (size_t)s * N3 + hh * HD;
    int   dp = (d < 36) ? d + 36 : d - 36;
    float sg = (d < 36) ? -1.f : 1.f;
    float q  = (float)row[d],        q2 = (float)row[dp];
    float k  = (float)row[HID + d],  k2 = (float)row[HID + dp];
    Qp[off] = (bf16)((q * c + sg * q2 * si) * 0.11785113019775793f);  // 72^-0.5 folded
    Kp[off] = (bf16)(k * c + sg * k2 * si);
}

// ---------------- pack V transposed: [h][80][4096] (rows 72..79 zero) ----------------
__global__ void pack_v(const bf16* __restrict__ qkv, bf16* __restrict__ Vp)
{
    __shared__ __align__(16) bf16 t[64][80];
    int h = blockIdx.y, s0 = blockIdx.x * 64;
    int tid = threadIdx.x;
    for (int i = tid; i < 64 * 9; i += 256) {         // 72 = 9 chunks of 8
        int sl = i / 9, c8 = (i % 9) * 8;
        *(bf16x8*)&t[sl][c8] =
            *(const bf16x8*)&qkv[(size_t)(s0 + sl) * N3 + 2 * HID + h * HD + c8];
    }
    __syncthreads();
    for (int i = tid; i < 80 * 8; i += 256) {         // 64 seq = 8 chunks of 8
        int d = i / 8, s8 = (i % 8) * 8;
        bf16x8 v;
#pragma unroll
        for (int j = 0; j < 8; ++j)
            v[j] = (d < HD) ? t[s8 + j][d] : (bf16)0.f;
        *(bf16x8*)&Vp[((size_t)h * HDV + d) * SEQ + s0 + s8] = v;
    }
}

// ---------------- flash attention: 4 waves x 16 q-rows, KBLK=64 ----------------
__global__ __launch_bounds__(256)
void attn_fwd(const bf16* __restrict__ Qp, const bf16* __restrict__ Kp,
              const bf16* __restrict__ Vp, bf16* __restrict__ Oout)
{
    __shared__ __align__(16) bf16 Ks[64 * 104];       // [key][d] pad 96->104 (2-way banks)
    __shared__ __align__(16) bf16 Vs[80 * 72];        // [d][key] pad 64->72
    __shared__ __align__(16) bf16 Ps[4][16 * 72];     // per-wave P [q][key] pad 64->72
    int h  = blockIdx.y;
    int q0 = blockIdx.x * 64;
    int tid = threadIdx.x, lane = tid & 63, w = tid >> 6;
    int lq = lane & 15, lk = lane >> 4;

    bf16x8 qf[3];
    const bf16* qb = Qp + ((size_t)h * SEQ + q0 + w * 16 + lq) * HDP + lk * 8;
#pragma unroll
    for (int t = 0; t < 3; ++t) qf[t] = *(const bf16x8*)(qb + t * 32);

    f32x4 o[5] = {};
    float mr[4] = {-1e30f, -1e30f, -1e30f, -1e30f};
    float lr[4] = {};

    for (int kt = 0; kt < SEQ; kt += 64) {
        __syncthreads();
        for (int i = tid; i < 64 * 12; i += 256) {    // K tile 64x96
            int r = i / 12, c8 = (i % 12) * 8;
            *(bf16x8*)&Ks[r * 104 + c8] =
                *(const bf16x8*)&Kp[((size_t)h * SEQ + kt + r) * HDP + c8];
        }
        for (int i = tid; i < 80 * 8; i += 256) {     // V tile 80x64 (transposed)
            int r = i / 8, c8 = (i % 8) * 8;
            *(bf16x8*)&Vs[r * 72 + c8] =
                *(const bf16x8*)&Vp[((size_t)h * HDV + r) * SEQ + kt + c8];
        }
        __syncthreads();

        // S = Q K^T  (lane holds S[row=lk*4+r][col=n*16+lq])
        f32x4 s[4];
#pragma unroll
        for (int n = 0; n < 4; ++n) {
            f32x4 a = {};
#pragma unroll
            for (int t = 0; t < 3; ++t) {
                bf16x8 kf = *(const bf16x8*)&Ks[(n * 16 + lq) * 104 + t * 32 + lk * 8];
                a = __builtin_amdgcn_mfma_f32_16x16x32_bf16(qf[t], kf, a, 0, 0, 0);
            }
            s[n] = a;
        }

        // online softmax: row stats across the 16 lanes sharing lk
        float tm[4];
#pragma unroll
        for (int r = 0; r < 4; ++r)
            tm[r] = fmaxf(fmaxf(s[0][r], s[1][r]), fmaxf(s[2][r], s[3][r]));
#pragma unroll
        for (int off = 1; off < 16; off <<= 1)
#pragma unroll
            for (int r = 0; r < 4; ++r)
                tm[r] = fmaxf(tm[r], __shfl_xor(tm[r], off));

        float fac[4], ts[4];
#pragma unroll
        for (int r = 0; r < 4; ++r) {
            float mn = fmaxf(mr[r], tm[r]);
            fac[r] = __expf(mr[r] - mn);
            mr[r] = mn;
            ts[r] = 0.f;
        }
#pragma unroll
        for (int n = 0; n < 4; ++n)
#pragma unroll
            for (int r = 0; r < 4; ++r) {
                float p = __expf(s[n][r] - mr[r]);
                bf16  pb = (bf16)p;
                ts[r] += (float)pb;   // consistent with bf16 P used in PV
                Ps[w][(lk * 4 + r) * 72 + n * 16 + lq] = pb;
            }
#pragma unroll
        for (int off = 1; off < 16; off <<= 1)
#pragma unroll
            for (int r = 0; r < 4; ++r)
                ts[r] += __shfl_xor(ts[r], off);
#pragma unroll
        for (int r = 0; r < 4; ++r)
            lr[r] = lr[r] * fac[r] + ts[r];

#pragma unroll
        for (int dt = 0; dt < 5; ++dt)
#pragma unroll
            for (int r = 0; r < 4; ++r)
                o[dt][r] *= fac[r];

        // PV: O += P * V
#pragma unroll
        for (int ks = 0; ks < 2; ++ks) {
            bf16x8 pf = *(const bf16x8*)&Ps[w][lq * 72 + ks * 32 + lk * 8];
#pragma unroll
            for (int dt = 0; dt < 5; ++dt) {
                bf16x8 vf = *(const bf16x8*)&Vs[(dt * 16 + lq) * 72 + ks * 32 + lk * 8];
                o[dt] = __builtin_amdgcn_mfma_f32_16x16x32_bf16(pf, vf, o[dt], 0, 0, 0);
            }
        }
    }

    // epilogue: out[row][h*72+d] = O/l (drop padded d)
#pragma unroll
    for (int dt = 0; dt < 5; ++dt) {
        int d = dt * 16 + lq;
        if (d < HD) {
#pragma unroll
            for (int r = 0; r < 4; ++r) {
                int row = q0 + w * 16 + lk * 4 + r;
                Oout[(size_t)row * HID + h * HD + d] = (bf16)(o[dt][r] / lr[r]);
            }
        }
    }
}

extern "C" void kernel_launch(void* const* d_in, const int* in_sizes, int n_in,
                              void* d_out, int out_size, void* d_ws, size_t ws_size,
                              hipStream_t stream)
{
    const float* hidden = (const float*)d_in[0];
    // d_in[1] = cu_seqlens: unused by the reference
    const float* cosT  = (const float*)d_in[2];
    const float* sinT  = (const float*)d_in[3];
    const float* Wqkv  = (const float*)d_in[4];
    const float* bqkv  = (const float*)d_in[5];
    const float* Wproj = (const float*)d_in[6];
    const float* bproj = (const float*)d_in[7];

    char* ws = (char*)d_ws;
    size_t off = 0;
    auto alloc = [&](size_t bytes) {
        char* p = ws + off;
        off += (bytes + 255) & ~(size_t)255;
        return p;
    };
    bf16* hid_b  = (bf16*)alloc((size_t)SEQ * HID * 2);   // reused as attn output later
    bf16* WqkvT  = (bf16*)alloc((size_t)N3  * HID * 2);
    bf16* WprojT = (bf16*)alloc((size_t)HID * HID * 2);
    bf16* qkv_b  = (bf16*)alloc((size_t)SEQ * N3  * 2);
    bf16* Qp     = (bf16*)alloc((size_t)NH * SEQ * HDP * 2);
    bf16* Kp     = (bf16*)alloc((size_t)NH * SEQ * HDP * 2);
    bf16* Vp     = (bf16*)alloc((size_t)NH * HDV * SEQ * 2);
    bf16* attno  = hid_b;  // overlay: hid_b dead after GEMM1

    cvt_bf16<<<SEQ * HID / (256 * 8), 256, 0, stream>>>(hidden, hid_b, SEQ * HID / 8);
    transpose_cvt<<<dim3(N3 / 32, HID / 32), 256, 0, stream>>>(Wqkv, WqkvT, HID, N3);
    transpose_cvt<<<dim3(HID / 32, HID / 32), 256, 0, stream>>>(Wproj, WprojT, HID, HID);
    gemm_bt<0><<<dim3(SEQ / 128, N3 / 128), 256, 0, stream>>>(hid_b, WqkvT, bqkv, qkv_b,
                                                              SEQ, N3, HID);
    rope_pack_qk<<<SEQ * NH * HDP / 256, 256, 0, stream>>>(qkv_b, cosT, sinT, Qp, Kp);
    pack_v<<<dim3(SEQ / 64, NH), 256, 0, stream>>>(qkv_b, Vp);
    attn_fwd<<<dim3(SEQ / 64, NH), 256, 0, stream>>>(Qp, Kp, Vp, attno);
    gemm_bt<1><<<dim3(SEQ / 128, HID / 128), 256, 0, stream>>>(attno, WprojT, bproj, d_out,
                                                               SEQ, HID, HID);
}

// Round 3
// 263.177 us; speedup vs baseline: 1.5576x; 1.5576x over previous
//
#include <hip/hip_runtime.h>
#include <hip/hip_bf16.h>
#include <stdint.h>

#define SEQ 4096
#define HID 1152
#define NH  16
#define HD  72
#define N3  3456
#define DQ  80     // Q padded head dim (5 x 16)
#define DK  128    // Kp row length (swizzle span = 16 chunks of 8)
#define DV  96     // V rows (3 x 32)
#define KVB 128    // keys per LDS tile
#define QBLK 128   // q rows per block (4 waves x 32)

typedef __bf16 bf16;
typedef __bf16 bf16x8 __attribute__((ext_vector_type(8)));
typedef float  f32x4  __attribute__((ext_vector_type(4)));
typedef float  f32x16 __attribute__((ext_vector_type(16)));

#define EXP2F(x) __builtin_amdgcn_exp2f(x)

__device__ __forceinline__ void gload_lds16(const void* g, void* l) {
    __builtin_amdgcn_global_load_lds(
        (__attribute__((address_space(1))) void*)(void*)g,
        (__attribute__((address_space(3))) void*)l, 16, 0, 0);
}
__device__ __forceinline__ uint16_t bfbits(float x) {
    return __builtin_bit_cast(uint16_t, (bf16)x);
}
__device__ __forceinline__ float bftof(uint16_t u) {
    return __builtin_bit_cast(float, (uint32_t)u << 16);
}

// ---------------- elementwise f32 -> bf16 (8/thread) ----------------
__global__ void cvt_bf16(const float* __restrict__ in, bf16* __restrict__ out, int n8)
{
    int i = blockIdx.x * 256 + threadIdx.x;
    if (i >= n8) return;
    const float4* p = (const float4*)in + (size_t)i * 2;
    float4 a = p[0], b = p[1];
    bf16x8 o;
    o[0]=(bf16)a.x; o[1]=(bf16)a.y; o[2]=(bf16)a.z; o[3]=(bf16)a.w;
    o[4]=(bf16)b.x; o[5]=(bf16)b.y; o[6]=(bf16)b.z; o[7]=(bf16)b.w;
    ((bf16x8*)out)[i] = o;
}

// ---------------- [R][C] f32 -> [C][R] bf16 (tiled transpose) ----------------
__global__ void transpose_cvt(const float* __restrict__ in, bf16* __restrict__ out, int R, int C)
{
    __shared__ float tl[32][33];
    int c0 = blockIdx.x * 32, r0 = blockIdx.y * 32;
    int tx = threadIdx.x & 31, ty = threadIdx.x >> 5;
#pragma unroll
    for (int i = 0; i < 4; ++i)
        tl[ty + 8*i][tx] = in[(size_t)(r0 + ty + 8*i) * C + c0 + tx];
    __syncthreads();
#pragma unroll
    for (int i = 0; i < 4; ++i)
        out[(size_t)(c0 + ty + 8*i) * R + r0 + tx] = (bf16)tl[tx][ty + 8*i];
}

// ---------------- GEMM: C[M][N] = A[M][K] * BT[N][K]^T + bias ----------------
template<int OUT_F32>
__global__ __launch_bounds__(256)
void gemm_bt(const bf16* __restrict__ A, const bf16* __restrict__ BT,
             const float* __restrict__ bias, void* __restrict__ out,
             int M, int N, int K)
{
    __shared__ __align__(16) bf16 As[128 * 32];
    __shared__ __align__(16) bf16 Bs[128 * 32];
    int tid = threadIdx.x;
    int lane = tid & 63, w = tid >> 6;
    int wm = w & 1, wn = w >> 1;
    int m0 = blockIdx.x * 128, n0 = blockIdx.y * 128;
    int lq = lane & 15, lk = lane >> 4;

    f32x4 acc[4][4] = {};

    for (int k0 = 0; k0 < K; k0 += 32) {
        __syncthreads();
#pragma unroll
        for (int i = 0; i < 2; ++i) {
            int c = w * 128 + i * 64 + lane;
            const bf16* ga = A  + (size_t)(m0 + (c >> 2)) * K + k0 + (c & 3) * 8;
            const bf16* gb = BT + (size_t)(n0 + (c >> 2)) * K + k0 + (c & 3) * 8;
            gload_lds16(ga, (char*)As + (w * 128 + i * 64) * 16);
            gload_lds16(gb, (char*)Bs + (w * 128 + i * 64) * 16);
        }
        __syncthreads();
        bf16x8 af[4], bfr[4];
#pragma unroll
        for (int m = 0; m < 4; ++m)
            af[m] = *(const bf16x8*)&As[(wm * 64 + m * 16 + lq) * 32 + lk * 8];
#pragma unroll
        for (int n = 0; n < 4; ++n)
            bfr[n] = *(const bf16x8*)&Bs[(wn * 64 + n * 16 + lq) * 32 + lk * 8];
#pragma unroll
        for (int m = 0; m < 4; ++m)
#pragma unroll
            for (int n = 0; n < 4; ++n)
                acc[m][n] = __builtin_amdgcn_mfma_f32_16x16x32_bf16(af[m], bfr[n], acc[m][n], 0, 0, 0);
    }

    int rb = m0 + wm * 64, cb = n0 + wn * 64;
#pragma unroll
    for (int m = 0; m < 4; ++m) {
#pragma unroll
        for (int n = 0; n < 4; ++n) {
            int col = cb + n * 16 + lq;
            float b = bias[col];
#pragma unroll
            for (int r = 0; r < 4; ++r) {
                int row = rb + m * 16 + lk * 4 + r;
                float v = acc[m][n][r] + b;
                if (OUT_F32) ((float*)out)[(size_t)row * N + col] = v;
                else         ((bf16*)out)[(size_t)row * N + col] = (bf16)v;
            }
        }
    }
}

// ------- RoPE + pack: Qp [h][s][80] (scale*log2e folded), Kp [h][s][128] swizzled -------
__global__ void rope_pack_qk2(const bf16* __restrict__ qkv, const float* __restrict__ cs,
                              const float* __restrict__ sn, bf16* __restrict__ Qp,
                              bf16* __restrict__ Kp)
{
    int idx = blockIdx.x * 256 + threadIdx.x;    // NH*SEQ*128
    int dd = idx & 127;
    int s  = (idx >> 7) & (SEQ - 1);
    int h  = idx >> 19;
    float qv = 0.f, kv = 0.f;
    if (dd < HD) {
        const bf16* row = qkv + (size_t)s * N3 + h * HD;
        float c  = cs[s * HD + dd], si = sn[s * HD + dd];
        int   dp = (dd < 36) ? dd + 36 : dd - 36;
        float sg = (dd < 36) ? -1.f : 1.f;
        float qa = (float)row[dd],       qb = (float)row[dp];
        float ka = (float)row[HID + dd], kb = (float)row[HID + dp];
        qv = (qa * c + sg * qb * si) * (0.11785113019775793f * 1.4426950408889634f);
        kv =  ka * c + sg * kb * si;
    }
    // store K pre-swizzled so (linear global_load_lds -> swizzled ds_read) recovers it
    Kp[((size_t)h * SEQ + s) * DK + (dd ^ ((s & 15) << 3))] = (bf16)kv;
    if (dd < DQ) Qp[((size_t)h * SEQ + s) * DQ + dd] = (bf16)qv;
}

// ------- pack V^T: Vp [h][96][4096], seq swizzled within 128-chunks, rows 72.. zero -------
__global__ void pack_v2(const bf16* __restrict__ qkv, bf16* __restrict__ Vp)
{
    __shared__ __align__(16) bf16 t[64][80];
    int h = blockIdx.y, s0 = blockIdx.x * 64;
    int tid = threadIdx.x;
    for (int i = tid; i < 64 * 9; i += 256) {
        int sl = i / 9, c8 = (i % 9) * 8;
        *(bf16x8*)&t[sl][c8] =
            *(const bf16x8*)&qkv[(size_t)(s0 + sl) * N3 + 2 * HID + h * HD + c8];
    }
    __syncthreads();
    for (int i = tid; i < DV * 8; i += 256) {
        int d = i / 8, s8 = (i % 8) * 8;
        bf16x8 v;
#pragma unroll
        for (int j = 0; j < 8; ++j) v[j] = (d < HD) ? t[s8 + j][d] : (bf16)0.f;
        int p = s0 + s8;
        int psw = (p & ~127) | ((p & 127) ^ ((d & 15) << 3));
        *(bf16x8*)&Vp[((size_t)h * DV + d) * SEQ + psw] = v;
    }
}

// ---------------- flash attention, swapped-QK^T 32x32x16, in-register softmax ----------------
__global__ __launch_bounds__(256)
void attn_fwd2(const bf16* __restrict__ Qp, const bf16* __restrict__ Kp,
               const bf16* __restrict__ Vp, bf16* __restrict__ Oout)
{
    __shared__ __align__(16) char smem[KVB * DK * 2 + DV * KVB * 2];  // 32KB + 24KB
    bf16* Ks = (bf16*)smem;
    bf16* Vs = (bf16*)(smem + KVB * DK * 2);

    const int h  = blockIdx.y;
    const int q0 = blockIdx.x * QBLK;
    const int tid = threadIdx.x, lane = tid & 63, w = tid >> 6;
    const int ql = lane & 31, hi = lane >> 5;
    const int q  = q0 + w * 32 + ql;

    // Q fragments (B-operand): Qf[ks][j] = Q[q][ks*16 + hi*8 + j]
    bf16x8 qf[5];
    const bf16* qbase = Qp + ((size_t)h * SEQ + q) * DQ + hi * 8;
#pragma unroll
    for (int ks = 0; ks < 5; ++ks) qf[ks] = *(const bf16x8*)(qbase + ks * 16);

    f32x16 o[3] = {};            // O^T accum: col = q (lane-scalar), rows = d
    float m = -1e30f, l = 0.f;   // in log2 domain (log2e folded into Q)

    const bf16* ksrc = Kp + (size_t)h * SEQ * DK;

    for (int kt = 0; kt < SEQ; kt += KVB) {
        __syncthreads();
        // stage K tile: contiguous 32KB, 2048 x 16B chunks
#pragma unroll
        for (int i = 0; i < 8; ++i) {
            int c = w * 512 + i * 64;
            gload_lds16(ksrc + (size_t)kt * DK + (size_t)(c + lane) * 8, (char*)Ks + c * 16);
        }
        // stage V tile: 96 rows x 256B, 1536 x 16B chunks
#pragma unroll
        for (int i = 0; i < 6; ++i) {
            int c  = w * 384 + i * 64;
            int cl = c + lane;
            int d  = cl >> 4, cc = cl & 15;
            gload_lds16(Vp + ((size_t)(h * DV + d)) * SEQ + kt + cc * 8, (char*)Vs + c * 16);
        }
        __syncthreads();

        for (int kb = 0; kb < 4; ++kb) {
            // ---- S^T = mfma(K, Q): lane holds S[q=ql][16 of 32 keys] ----
            f32x16 s = {};
            int krow = kb * 32 + ql;
            int ksw  = (krow & 15) << 4;
            const char* krp = (const char*)Ks + krow * 256;
#pragma unroll
            for (int ks = 0; ks < 5; ++ks) {
                bf16x8 kf = *(const bf16x8*)(krp + ((ks * 32 + hi * 16) ^ ksw));
                s = __builtin_amdgcn_mfma_f32_32x32x16_bf16(kf, qf[ks], s, 0, 0, 0);
            }

            // ---- online softmax (lane-local row, partner lane^32 holds other 16 keys) ----
            float pmax = s[0];
#pragma unroll
            for (int r = 1; r < 16; ++r) pmax = fmaxf(pmax, s[r]);
            pmax = fmaxf(pmax, __shfl_xor(pmax, 32));
            if (__any(pmax > m + 11.0f)) {           // defer-max (T13), THR~8 nats
                float nm  = fmaxf(m, pmax);
                float fac = EXP2F(m - nm);
                m = nm; l *= fac;
#pragma unroll
                for (int db = 0; db < 3; ++db)
#pragma unroll
                    for (int r = 0; r < 16; ++r) o[db][r] *= fac;
            }
            float ts = 0.f;
            uint32_t wd[8];
#pragma unroll
            for (int i = 0; i < 8; ++i) {
                uint16_t b0 = bfbits(EXP2F(s[2*i]   - m));
                uint16_t b1 = bfbits(EXP2F(s[2*i+1] - m));
                wd[i] = (uint32_t)b0 | ((uint32_t)b1 << 16);
                ts += bftof(b0) + bftof(b1);         // sum the bf16-rounded P
            }
            ts += __shfl_xor(ts, 32);
            l  += ts;

            // ---- build PV B-fragments in-register (key-halves exchange via lane^32) ----
            uint32_t r0 = __shfl_xor(hi ? wd[0] : wd[2], 32);
            uint32_t r1 = __shfl_xor(hi ? wd[1] : wd[3], 32);
            uint32_t r2 = __shfl_xor(hi ? wd[4] : wd[6], 32);
            uint32_t r3 = __shfl_xor(hi ? wd[5] : wd[7], 32);
            union { uint32_t u[4]; bf16x8 v; } pa0, pa1;
            pa0.u[0] = hi ? r0 : wd[0];  pa0.u[1] = hi ? r1 : wd[1];
            pa0.u[2] = hi ? wd[2] : r0;  pa0.u[3] = hi ? wd[3] : r1;
            pa1.u[0] = hi ? r2 : wd[4];  pa1.u[1] = hi ? r3 : wd[5];
            pa1.u[2] = hi ? wd[6] : r2;  pa1.u[3] = hi ? wd[7] : r3;

            // ---- O^T += mfma(V^T, P) ----
#pragma unroll
            for (int db = 0; db < 3; ++db) {
                int vrow = db * 32 + ql;
                const char* vrp = (const char*)Vs + vrow * 256;
                int vsw = (vrow & 15) << 4;
                bf16x8 v0 = *(const bf16x8*)(vrp + ((kb * 64      + hi * 16) ^ vsw));
                o[db] = __builtin_amdgcn_mfma_f32_32x32x16_bf16(v0, pa0.v, o[db], 0, 0, 0);
                bf16x8 v1 = *(const bf16x8*)(vrp + ((kb * 64 + 32 + hi * 16) ^ vsw));
                o[db] = __builtin_amdgcn_mfma_f32_32x32x16_bf16(v1, pa1.v, o[db], 0, 0, 0);
            }
        }
    }

    // ---- epilogue: LDS transpose then coalesced store ----
    __syncthreads();
    bf16* Os = (bf16*)smem;                 // [QBLK][80] stride 160B
    float invl = 1.0f / l;
    int qloc = w * 32 + ql;
#pragma unroll
    for (int db = 0; db < 3; ++db) {
#pragma unroll
        for (int r = 0; r < 16; ++r) {
            int dloc = (r & 3) + 8 * (r >> 2) + 4 * hi;
            int d = db * 32 + dloc;
            if (d < HD) Os[qloc * 80 + d] = (bf16)(o[db][r] * invl);
        }
    }
    __syncthreads();
    for (int i = tid; i < QBLK * 36; i += 256) {
        int row = i / 36, c = i % 36;
        uint32_t val = *(const uint32_t*)((const char*)Os + row * 160 + c * 4);
        *(uint32_t*)((char*)Oout + (size_t)(q0 + row) * 2304 + h * 144 + c * 4) = val;
    }
}

extern "C" void kernel_launch(void* const* d_in, const int* in_sizes, int n_in,
                              void* d_out, int out_size, void* d_ws, size_t ws_size,
                              hipStream_t stream)
{
    const float* hidden = (const float*)d_in[0];
    // d_in[1] = cu_seqlens: unused by the reference
    const float* cosT  = (const float*)d_in[2];
    const float* sinT  = (const float*)d_in[3];
    const float* Wqkv  = (const float*)d_in[4];
    const float* bqkv  = (const float*)d_in[5];
    const float* Wproj = (const float*)d_in[6];
    const float* bproj = (const float*)d_in[7];

    char* ws = (char*)d_ws;
    size_t off = 0;
    auto alloc = [&](size_t bytes) {
        char* p = ws + off;
        off += (bytes + 255) & ~(size_t)255;
        return p;
    };
    bf16* hid_b  = (bf16*)alloc((size_t)SEQ * HID * 2);
    bf16* WqkvT  = (bf16*)alloc((size_t)N3  * HID * 2);
    bf16* WprojT = (bf16*)alloc((size_t)HID * HID * 2);
    bf16* qkv_b  = (bf16*)alloc((size_t)SEQ * N3  * 2);
    bf16* Qp     = (bf16*)alloc((size_t)NH * SEQ * DQ * 2);
    bf16* Kp     = (bf16*)alloc((size_t)NH * SEQ * DK * 2);
    bf16* Vp     = (bf16*)alloc((size_t)NH * DV * SEQ * 2);
    bf16* attno  = hid_b;  // overlay: hid_b dead after GEMM1

    cvt_bf16<<<SEQ * HID / (256 * 8), 256, 0, stream>>>(hidden, hid_b, SEQ * HID / 8);
    transpose_cvt<<<dim3(N3 / 32, HID / 32), 256, 0, stream>>>(Wqkv, WqkvT, HID, N3);
    transpose_cvt<<<dim3(HID / 32, HID / 32), 256, 0, stream>>>(Wproj, WprojT, HID, HID);
    gemm_bt<0><<<dim3(SEQ / 128, N3 / 128), 256, 0, stream>>>(hid_b, WqkvT, bqkv, qkv_b,
                                                              SEQ, N3, HID);
    rope_pack_qk2<<<NH * SEQ * 128 / 256, 256, 0, stream>>>(qkv_b, cosT, sinT, Qp, Kp);
    pack_v2<<<dim3(SEQ / 64, NH), 256, 0, stream>>>(qkv_b, Vp);
    attn_fwd2<<<dim3(SEQ / QBLK, NH), 256, 0, stream>>>(Qp, Kp, Vp, attno);
    gemm_bt<1><<<dim3(SEQ / 128, HID / 128), 256, 0, stream>>>(attno, WprojT, bproj, d_out,
                                                               SEQ, HID, HID);
}

// Round 4
// 249.411 us; speedup vs baseline: 1.6436x; 1.0552x over previous
//
#include <hip/hip_runtime.h>
#include <hip/hip_bf16.h>
#include <stdint.h>

#define SEQ 4096
#define HID 1152
#define NH  16
#define HD  72
#define N3  3456
#define DQ  80     // Q padded head dim (5 x 16)
#define DK  128    // Kp row length (16 chunks of 8, pow2 swizzle span)
#define DV  96     // V rows (3 x 32); row 72 = ones (l via MFMA), 73..95 zero
#define QBLK 128   // q rows per block (4 wave-groups x 32)

typedef __bf16 bf16;
typedef __bf16 bf16x8 __attribute__((ext_vector_type(8)));
typedef float  f32x4  __attribute__((ext_vector_type(4)));
typedef float  f32x16 __attribute__((ext_vector_type(16)));

#define EXP2F(x) __builtin_amdgcn_exp2f(x)

__device__ __forceinline__ void gload_lds16(const void* g, void* l) {
    __builtin_amdgcn_global_load_lds(
        (__attribute__((address_space(1))) void*)(void*)g,
        (__attribute__((address_space(3))) void*)l, 16, 0, 0);
}
__device__ __forceinline__ uint16_t bfbits(float x) {
    return __builtin_bit_cast(uint16_t, (bf16)x);
}

// ---------------- elementwise f32 -> bf16 (8/thread) ----------------
__global__ void cvt_bf16(const float* __restrict__ in, bf16* __restrict__ out, int n8)
{
    int i = blockIdx.x * 256 + threadIdx.x;
    if (i >= n8) return;
    const float4* p = (const float4*)in + (size_t)i * 2;
    float4 a = p[0], b = p[1];
    bf16x8 o;
    o[0]=(bf16)a.x; o[1]=(bf16)a.y; o[2]=(bf16)a.z; o[3]=(bf16)a.w;
    o[4]=(bf16)b.x; o[5]=(bf16)b.y; o[6]=(bf16)b.z; o[7]=(bf16)b.w;
    ((bf16x8*)out)[i] = o;
}

// ---------------- [R][C] f32 -> [C][R] bf16 (tiled transpose) ----------------
__global__ void transpose_cvt(const float* __restrict__ in, bf16* __restrict__ out, int R, int C)
{
    __shared__ float tl[32][33];
    int c0 = blockIdx.x * 32, r0 = blockIdx.y * 32;
    int tx = threadIdx.x & 31, ty = threadIdx.x >> 5;
#pragma unroll
    for (int i = 0; i < 4; ++i)
        tl[ty + 8*i][tx] = in[(size_t)(r0 + ty + 8*i) * C + c0 + tx];
    __syncthreads();
#pragma unroll
    for (int i = 0; i < 4; ++i)
        out[(size_t)(c0 + ty + 8*i) * R + r0 + tx] = (bf16)tl[tx][ty + 8*i];
}

// ---------------- GEMM: C[M][N] = A[M][K] * BT[N][K]^T + bias ----------------
template<int OUT_F32>
__global__ __launch_bounds__(256)
void gemm_bt(const bf16* __restrict__ A, const bf16* __restrict__ BT,
             const float* __restrict__ bias, void* __restrict__ out,
             int M, int N, int K)
{
    __shared__ __align__(16) bf16 As[128 * 32];
    __shared__ __align__(16) bf16 Bs[128 * 32];
    int tid = threadIdx.x;
    int lane = tid & 63, w = tid >> 6;
    int wm = w & 1, wn = w >> 1;
    int m0 = blockIdx.x * 128, n0 = blockIdx.y * 128;
    int lq = lane & 15, lk = lane >> 4;

    f32x4 acc[4][4] = {};

    for (int k0 = 0; k0 < K; k0 += 32) {
        __syncthreads();
#pragma unroll
        for (int i = 0; i < 2; ++i) {
            int c = w * 128 + i * 64 + lane;
            const bf16* ga = A  + (size_t)(m0 + (c >> 2)) * K + k0 + (c & 3) * 8;
            const bf16* gb = BT + (size_t)(n0 + (c >> 2)) * K + k0 + (c & 3) * 8;
            gload_lds16(ga, (char*)As + (w * 128 + i * 64) * 16);
            gload_lds16(gb, (char*)Bs + (w * 128 + i * 64) * 16);
        }
        __syncthreads();
        bf16x8 af[4], bfr[4];
#pragma unroll
        for (int m = 0; m < 4; ++m)
            af[m] = *(const bf16x8*)&As[(wm * 64 + m * 16 + lq) * 32 + lk * 8];
#pragma unroll
        for (int n = 0; n < 4; ++n)
            bfr[n] = *(const bf16x8*)&Bs[(wn * 64 + n * 16 + lq) * 32 + lk * 8];
#pragma unroll
        for (int m = 0; m < 4; ++m)
#pragma unroll
            for (int n = 0; n < 4; ++n)
                acc[m][n] = __builtin_amdgcn_mfma_f32_16x16x32_bf16(af[m], bfr[n], acc[m][n], 0, 0, 0);
    }

    int rb = m0 + wm * 64, cb = n0 + wn * 64;
#pragma unroll
    for (int m = 0; m < 4; ++m) {
#pragma unroll
        for (int n = 0; n < 4; ++n) {
            int col = cb + n * 16 + lq;
            float b = bias[col];
#pragma unroll
            for (int r = 0; r < 4; ++r) {
                int row = rb + m * 16 + lk * 4 + r;
                float v = acc[m][n][r] + b;
                if (OUT_F32) ((float*)out)[(size_t)row * N + col] = v;
                else         ((bf16*)out)[(size_t)row * N + col] = (bf16)v;
            }
        }
    }
}

// ------- RoPE + pack: Qp [h][s][80] (scale*log2e folded), Kp [h][s][128] swizzled -------
__global__ void rope_pack_qk2(const bf16* __restrict__ qkv, const float* __restrict__ cs,
                              const float* __restrict__ sn, bf16* __restrict__ Qp,
                              bf16* __restrict__ Kp)
{
    int idx = blockIdx.x * 256 + threadIdx.x;    // NH*SEQ*128
    int dd = idx & 127;
    int s  = (idx >> 7) & (SEQ - 1);
    int h  = idx >> 19;
    float qv = 0.f, kv = 0.f;
    if (dd < HD) {
        const bf16* row = qkv + (size_t)s * N3 + h * HD;
        float c  = cs[s * HD + dd], si = sn[s * HD + dd];
        int   dp = (dd < 36) ? dd + 36 : dd - 36;
        float sg = (dd < 36) ? -1.f : 1.f;
        float qa = (float)row[dd],       qb = (float)row[dp];
        float ka = (float)row[HID + dd], kb = (float)row[HID + dp];
        qv = (qa * c + sg * qb * si) * (0.11785113019775793f * 1.4426950408889634f);
        kv =  ka * c + sg * kb * si;
    }
    // store K pre-swizzled so (linear global_load_lds -> swizzled ds_read) recovers it
    Kp[((size_t)h * SEQ + s) * DK + (dd ^ ((s & 15) << 3))] = (bf16)kv;
    if (dd < DQ) Qp[((size_t)h * SEQ + s) * DQ + dd] = (bf16)qv;
}

// ------- pack V^T: Vp [h][96][4096], seq pre-swizzled per 64-key group -------
// row 72 = all-ones (l accumulates via MFMA), rows 73..95 zero
__global__ void pack_v2(const bf16* __restrict__ qkv, bf16* __restrict__ Vp)
{
    __shared__ __align__(16) bf16 t[64][80];
    int h = blockIdx.y, s0 = blockIdx.x * 64;
    int tid = threadIdx.x;
    for (int i = tid; i < 64 * 9; i += 256) {
        int sl = i / 9, c8 = (i % 9) * 8;
        *(bf16x8*)&t[sl][c8] =
            *(const bf16x8*)&qkv[(size_t)(s0 + sl) * N3 + 2 * HID + h * HD + c8];
    }
    __syncthreads();
    for (int i = tid; i < DV * 8; i += 256) {
        int d = i / 8, c = i % 8;                 // chunk c = keys 8c..8c+7 within 64-group
        bf16x8 v;
#pragma unroll
        for (int j = 0; j < 8; ++j)
            v[j] = (d < HD) ? t[c * 8 + j][d] : ((d == 72) ? (bf16)1.f : (bf16)0.f);
        int csw = c ^ (d & 7);                    // pre-swizzle within 64-key group
        *(bf16x8*)&Vp[((size_t)h * DV + d) * SEQ + s0 + csw * 8] = v;
    }
}

// -------- flash attention: 8 waves, K-split (even/odd 64-key tiles), in-reg softmax --------
// LDS: [K0 16K][K1 16K][V0 12K][V1 12K] = 56KB
__global__ __launch_bounds__(512, 4)
void attn_fwd3(const bf16* __restrict__ Qp, const bf16* __restrict__ Kp,
               const bf16* __restrict__ Vp, bf16* __restrict__ Oout)
{
    __shared__ __align__(16) char smem[57344];

    const int h  = blockIdx.y;
    const int q0 = blockIdx.x * QBLK;
    const int tid = threadIdx.x, lane = tid & 63, w = tid >> 6;
    const int wg = w & 3, kh = w >> 2;           // q-sub-tile, K-half
    const int ql = lane & 31, hi = lane >> 5;
    const int q  = q0 + wg * 32 + ql;

    bf16x8 qf[5];
    const bf16* qbase = Qp + ((size_t)h * SEQ + q) * DQ + hi * 8;
#pragma unroll
    for (int ks = 0; ks < 5; ++ks) qf[ks] = *(const bf16x8*)(qbase + ks * 16);

    f32x16 o[3] = {};            // O^T accum: col=q (lane-scalar), rows=d; row 72 carries l
    float m = -1e30f;            // log2 domain

    const bf16* ksrc = Kp + (size_t)h * SEQ * DK;
    const bf16* vsrc = Vp + (size_t)h * DV * SEQ;
    const char* myK = smem + kh * 16384;
    const char* myV = smem + 32768 + kh * 12288;

    for (int t2 = 0; t2 < SEQ / 128; ++t2) {
        __syncthreads();
        // stage both 64-key tiles: K 2x1024 chunks + V 2x768 chunks = 56 runs of 64
#pragma unroll
        for (int i = 0; i < 7; ++i) {
            int r = i * 8 + w;
            if (r < 32) {
                int b  = r >> 4;
                int c0 = (r & 15) * 64;
                gload_lds16(ksrc + (size_t)(t2 * 128 + b * 64) * DK + (size_t)(c0 + lane) * 8,
                            smem + b * 16384 + c0 * 16);
            } else {
                int rr = r - 32;
                int b  = rr / 12;
                int c0 = (rr % 12) * 64;
                int cl = c0 + lane;
                int d = cl >> 3, cc = cl & 7;
                gload_lds16(vsrc + (size_t)d * SEQ + t2 * 128 + b * 64 + cc * 8,
                            smem + 32768 + b * 12288 + c0 * 16);
            }
        }
        __syncthreads();

        for (int kb = 0; kb < 2; ++kb) {
            // ---- S^T = mfma(K, Q) ----
            f32x16 s = {};
            int krow = kb * 32 + ql;
            int ksw  = krow & 15;
            const char* krp = myK + krow * 256;
#pragma unroll
            for (int ks = 0; ks < 5; ++ks) {
                bf16x8 kf = *(const bf16x8*)(krp + (((ks * 2 + hi) ^ ksw) * 16));
                s = __builtin_amdgcn_mfma_f32_32x32x16_bf16(kf, qf[ks], s, 0, 0, 0);
            }

            // ---- online softmax (row = lane-local; partner lane^32 holds other 16 keys) ----
            float pmax = fmaxf(fmaxf(s[0], s[1]), s[2]);
#pragma unroll
            for (int r = 3; r < 16; r += 2) pmax = fmaxf(fmaxf(pmax, s[r]), s[r + 1]);
            pmax = fmaxf(pmax, __shfl_xor(pmax, 32));
            if (__any(pmax > m + 11.0f)) {        // defer-max (T13)
                float nm  = fmaxf(m, pmax);
                float fac = EXP2F(m - nm);
                m = nm;
#pragma unroll
                for (int db = 0; db < 3; ++db)
#pragma unroll
                    for (int r = 0; r < 16; ++r) o[db][r] *= fac;
            }
            uint32_t wd[8];
#pragma unroll
            for (int i = 0; i < 8; ++i) {
                uint16_t b0 = bfbits(EXP2F(s[2*i]   - m));
                uint16_t b1 = bfbits(EXP2F(s[2*i+1] - m));
                wd[i] = (uint32_t)b0 | ((uint32_t)b1 << 16);
            }

            // ---- build PV B-fragments in-register (halves exchange via lane^32) ----
            uint32_t r0 = __shfl_xor(hi ? wd[0] : wd[2], 32);
            uint32_t r1 = __shfl_xor(hi ? wd[1] : wd[3], 32);
            uint32_t r2 = __shfl_xor(hi ? wd[4] : wd[6], 32);
            uint32_t r3 = __shfl_xor(hi ? wd[5] : wd[7], 32);
            union { uint32_t u[4]; bf16x8 v; } pa0, pa1;
            pa0.u[0] = hi ? r0 : wd[0];  pa0.u[1] = hi ? r1 : wd[1];
            pa0.u[2] = hi ? wd[2] : r0;  pa0.u[3] = hi ? wd[3] : r1;
            pa1.u[0] = hi ? r2 : wd[4];  pa1.u[1] = hi ? r3 : wd[5];
            pa1.u[2] = hi ? wd[6] : r2;  pa1.u[3] = hi ? wd[7] : r3;

            // ---- O^T += mfma(V^T, P)  (V row 72 = ones -> accumulates l) ----
#pragma unroll
            for (int db = 0; db < 3; ++db) {
                int vrow = db * 32 + ql;
                int vsw  = vrow & 7;
                const char* vrp = myV + vrow * 128;
                bf16x8 v0 = *(const bf16x8*)(vrp + (((kb * 4 + hi)     ^ vsw) * 16));
                o[db] = __builtin_amdgcn_mfma_f32_32x32x16_bf16(v0, pa0.v, o[db], 0, 0, 0);
                bf16x8 v1 = *(const bf16x8*)(vrp + (((kb * 4 + 2 + hi) ^ vsw) * 16));
                o[db] = __builtin_amdgcn_mfma_f32_32x32x16_bf16(v1, pa1.v, o[db], 0, 0, 0);
            }
        }
    }

    // ---- merge the two K-half partials (l rides inside o[2]) ----
    __syncthreads();
    float* Lm = (float*)smem;                      // [8][64]
    float* Lo = (float*)(smem + 2048);             // [4][64][48]
    Lm[w * 64 + lane] = m;
    __syncthreads();
    {
        float ma = Lm[wg * 64 + lane], mb = Lm[(wg + 4) * 64 + lane];
        float mm = fmaxf(ma, mb);
        float fac = EXP2F(m - mm);
#pragma unroll
        for (int db = 0; db < 3; ++db)
#pragma unroll
            for (int r = 0; r < 16; ++r) o[db][r] *= fac;
    }
    if (kh == 1) {
        float* dst = Lo + ((size_t)(wg * 64 + lane)) * 48;
#pragma unroll
        for (int db = 0; db < 3; ++db)
#pragma unroll
            for (int r = 0; r < 16; ++r) dst[db * 16 + r] = o[db][r];
    }
    __syncthreads();
    if (kh == 0) {
        const float* src = Lo + ((size_t)(wg * 64 + lane)) * 48;
#pragma unroll
        for (int db = 0; db < 3; ++db)
#pragma unroll
            for (int r = 0; r < 16; ++r) o[db][r] += src[db * 16 + r];
    }
    __syncthreads();

    // ---- epilogue: kh==0 waves own the merged state; LDS transpose, coalesced store ----
    bf16* Os = (bf16*)smem;                        // [QBLK][80]
    if (kh == 0) {
        float lv = o[2][4];                        // d=72 row: l (hi=0 lanes)
        float lo_ = __shfl_xor(lv, 32);
        float invl = 1.0f / (hi ? lo_ : lv);
        int qloc = wg * 32 + ql;
#pragma unroll
        for (int db = 0; db < 3; ++db) {
#pragma unroll
            for (int r = 0; r < 16; ++r) {
                int dloc = (r & 3) + 8 * (r >> 2) + 4 * hi;
                int d = db * 32 + dloc;
                if (d < HD) Os[qloc * 80 + d] = (bf16)(o[db][r] * invl);
            }
        }
    }
    __syncthreads();
    for (int i = tid; i < QBLK * 36; i += 512) {
        int row = i / 36, c = i % 36;
        uint32_t val = *(const uint32_t*)((const char*)Os + row * 160 + c * 4);
        *(uint32_t*)((char*)Oout + (size_t)(q0 + row) * 2304 + h * 144 + c * 4) = val;
    }
}

extern "C" void kernel_launch(void* const* d_in, const int* in_sizes, int n_in,
                              void* d_out, int out_size, void* d_ws, size_t ws_size,
                              hipStream_t stream)
{
    const float* hidden = (const float*)d_in[0];
    // d_in[1] = cu_seqlens: unused by the reference
    const float* cosT  = (const float*)d_in[2];
    const float* sinT  = (const float*)d_in[3];
    const float* Wqkv  = (const float*)d_in[4];
    const float* bqkv  = (const float*)d_in[5];
    const float* Wproj = (const float*)d_in[6];
    const float* bproj = (const float*)d_in[7];

    char* ws = (char*)d_ws;
    size_t off = 0;
    auto alloc = [&](size_t bytes) {
        char* p = ws + off;
        off += (bytes + 255) & ~(size_t)255;
        return p;
    };
    bf16* hid_b  = (bf16*)alloc((size_t)SEQ * HID * 2);
    bf16* WqkvT  = (bf16*)alloc((size_t)N3  * HID * 2);
    bf16* WprojT = (bf16*)alloc((size_t)HID * HID * 2);
    bf16* qkv_b  = (bf16*)alloc((size_t)SEQ * N3  * 2);
    bf16* Qp     = (bf16*)alloc((size_t)NH * SEQ * DQ * 2);
    bf16* Kp     = (bf16*)alloc((size_t)NH * SEQ * DK * 2);
    bf16* Vp     = (bf16*)alloc((size_t)NH * DV * SEQ * 2);
    bf16* attno  = hid_b;  // overlay: hid_b dead after GEMM1

    cvt_bf16<<<SEQ * HID / (256 * 8), 256, 0, stream>>>(hidden, hid_b, SEQ * HID / 8);
    transpose_cvt<<<dim3(N3 / 32, HID / 32), 256, 0, stream>>>(Wqkv, WqkvT, HID, N3);
    transpose_cvt<<<dim3(HID / 32, HID / 32), 256, 0, stream>>>(Wproj, WprojT, HID, HID);
    gemm_bt<0><<<dim3(SEQ / 128, N3 / 128), 256, 0, stream>>>(hid_b, WqkvT, bqkv, qkv_b,
                                                              SEQ, N3, HID);
    rope_pack_qk2<<<NH * SEQ * 128 / 256, 256, 0, stream>>>(qkv_b, cosT, sinT, Qp, Kp);
    pack_v2<<<dim3(SEQ / 64, NH), 256, 0, stream>>>(qkv_b, Vp);
    attn_fwd3<<<dim3(SEQ / QBLK, NH), 512, 0, stream>>>(Qp, Kp, Vp, attno);
    gemm_bt<1><<<dim3(SEQ / 128, HID / 128), 256, 0, stream>>>(attno, WprojT, bproj, d_out,
                                                               SEQ, HID, HID);
}

// Round 5
// 248.412 us; speedup vs baseline: 1.6502x; 1.0040x over previous
//
#include <hip/hip_runtime.h>
#include <hip/hip_bf16.h>
#include <stdint.h>

#define SEQ 4096
#define HID 1152
#define NH  16
#define HD  72
#define N3  3456
#define DQ  80     // Q padded head dim (5 x 16)
#define DK  128    // Kp row length (16 chunks of 8, pow2 swizzle span)
#define DV  96     // V rows used by PV (3 x 32); row 72 = ones (l via MFMA)
#define DVP 128    // Vp allocated row count (staging uniformity pad)
#define QBLK 256   // q rows per block (8 waves x 32)

typedef __bf16 bf16;
typedef __bf16 bf16x8 __attribute__((ext_vector_type(8)));
typedef float  f32x4  __attribute__((ext_vector_type(4)));
typedef float  f32x16 __attribute__((ext_vector_type(16)));

#define EXP2F(x) __builtin_amdgcn_exp2f(x)

__device__ __forceinline__ void gload_lds16(const void* g, void* l) {
    __builtin_amdgcn_global_load_lds(
        (__attribute__((address_space(1))) void*)(void*)g,
        (__attribute__((address_space(3))) void*)l, 16, 0, 0);
}
__device__ __forceinline__ uint16_t bfbits(float x) {
    return __builtin_bit_cast(uint16_t, (bf16)x);
}

// bijective XCD swizzle (nwg % 8 == 0 for every launch below)
__device__ __forceinline__ int xcd_swz(int orig, int nwg) {
    return (orig & 7) * (nwg >> 3) + (orig >> 3);
}

// ---------------- elementwise f32 -> bf16 (8/thread) ----------------
__global__ void cvt_bf16(const float* __restrict__ in, bf16* __restrict__ out, int n8)
{
    int i = blockIdx.x * 256 + threadIdx.x;
    if (i >= n8) return;
    const float4* p = (const float4*)in + (size_t)i * 2;
    float4 a = p[0], b = p[1];
    bf16x8 o;
    o[0]=(bf16)a.x; o[1]=(bf16)a.y; o[2]=(bf16)a.z; o[3]=(bf16)a.w;
    o[4]=(bf16)b.x; o[5]=(bf16)b.y; o[6]=(bf16)b.z; o[7]=(bf16)b.w;
    ((bf16x8*)out)[i] = o;
}

// ---------------- [R][C] f32 -> [C][R] bf16 (tiled transpose) ----------------
__global__ void transpose_cvt(const float* __restrict__ in, bf16* __restrict__ out, int R, int C)
{
    __shared__ float tl[32][33];
    int c0 = blockIdx.x * 32, r0 = blockIdx.y * 32;
    int tx = threadIdx.x & 31, ty = threadIdx.x >> 5;
#pragma unroll
    for (int i = 0; i < 4; ++i)
        tl[ty + 8*i][tx] = in[(size_t)(r0 + ty + 8*i) * C + c0 + tx];
    __syncthreads();
#pragma unroll
    for (int i = 0; i < 4; ++i)
        out[(size_t)(c0 + ty + 8*i) * R + r0 + tx] = (bf16)tl[tx][ty + 8*i];
}

// ---------------- GEMM: C[M][N] = A[M][K] * BT[N][K]^T + bias ----------------
template<int OUT_F32>
__global__ __launch_bounds__(256)
void gemm_bt(const bf16* __restrict__ A, const bf16* __restrict__ BT,
             const float* __restrict__ bias, void* __restrict__ out,
             int M, int N, int K)
{
    __shared__ __align__(16) bf16 As[128 * 32];
    __shared__ __align__(16) bf16 Bs[128 * 32];
    int tid = threadIdx.x;
    int lane = tid & 63, w = tid >> 6;
    int wm = w & 1, wn = w >> 1;
    // T1: XCD-aware bijective swizzle for L2 panel locality
    int nwg  = gridDim.x * gridDim.y;
    int wgid = xcd_swz(blockIdx.y * gridDim.x + blockIdx.x, nwg);
    int m0 = (wgid % gridDim.x) * 128, n0 = (wgid / gridDim.x) * 128;
    int lq = lane & 15, lk = lane >> 4;

    f32x4 acc[4][4] = {};

    for (int k0 = 0; k0 < K; k0 += 32) {
        __syncthreads();
#pragma unroll
        for (int i = 0; i < 2; ++i) {
            int c = w * 128 + i * 64 + lane;
            const bf16* ga = A  + (size_t)(m0 + (c >> 2)) * K + k0 + (c & 3) * 8;
            const bf16* gb = BT + (size_t)(n0 + (c >> 2)) * K + k0 + (c & 3) * 8;
            gload_lds16(ga, (char*)As + (w * 128 + i * 64) * 16);
            gload_lds16(gb, (char*)Bs + (w * 128 + i * 64) * 16);
        }
        __syncthreads();
        bf16x8 af[4], bfr[4];
#pragma unroll
        for (int m = 0; m < 4; ++m)
            af[m] = *(const bf16x8*)&As[(wm * 64 + m * 16 + lq) * 32 + lk * 8];
#pragma unroll
        for (int n = 0; n < 4; ++n)
            bfr[n] = *(const bf16x8*)&Bs[(wn * 64 + n * 16 + lq) * 32 + lk * 8];
#pragma unroll
        for (int m = 0; m < 4; ++m)
#pragma unroll
            for (int n = 0; n < 4; ++n)
                acc[m][n] = __builtin_amdgcn_mfma_f32_16x16x32_bf16(af[m], bfr[n], acc[m][n], 0, 0, 0);
    }

    int rb = m0 + wm * 64, cb = n0 + wn * 64;
#pragma unroll
    for (int m = 0; m < 4; ++m) {
#pragma unroll
        for (int n = 0; n < 4; ++n) {
            int col = cb + n * 16 + lq;
            float b = bias[col];
#pragma unroll
            for (int r = 0; r < 4; ++r) {
                int row = rb + m * 16 + lk * 4 + r;
                float v = acc[m][n][r] + b;
                if (OUT_F32) ((float*)out)[(size_t)row * N + col] = v;
                else         ((bf16*)out)[(size_t)row * N + col] = (bf16)v;
            }
        }
    }
}

// ------- RoPE + pack: Qp [h][s][80] (scale*log2e folded), Kp [h][s][128] swizzled -------
__global__ void rope_pack_qk2(const bf16* __restrict__ qkv, const float* __restrict__ cs,
                              const float* __restrict__ sn, bf16* __restrict__ Qp,
                              bf16* __restrict__ Kp)
{
    int idx = blockIdx.x * 256 + threadIdx.x;    // NH*SEQ*128
    int dd = idx & 127;
    int s  = (idx >> 7) & (SEQ - 1);
    int h  = idx >> 19;
    float qv = 0.f, kv = 0.f;
    if (dd < HD) {
        const bf16* row = qkv + (size_t)s * N3 + h * HD;
        float c  = cs[s * HD + dd], si = sn[s * HD + dd];
        int   dp = (dd < 36) ? dd + 36 : dd - 36;
        float sg = (dd < 36) ? -1.f : 1.f;
        float qa = (float)row[dd],       qb = (float)row[dp];
        float ka = (float)row[HID + dd], kb = (float)row[HID + dp];
        qv = (qa * c + sg * qb * si) * (0.11785113019775793f * 1.4426950408889634f);
        kv =  ka * c + sg * kb * si;
    }
    // store K pre-swizzled so (linear global_load_lds -> swizzled ds_read) recovers it
    Kp[((size_t)h * SEQ + s) * DK + (dd ^ ((s & 15) << 3))] = (bf16)kv;
    if (dd < DQ) Qp[((size_t)h * SEQ + s) * DQ + dd] = (bf16)qv;
}

// ------- pack V^T: Vp [h][128][4096] (rows 0..95 written), seq pre-swizzled per 64 -------
// row 72 = all-ones (l accumulates via MFMA), rows 73..95 zero, 96..127 never read
__global__ void pack_v2(const bf16* __restrict__ qkv, bf16* __restrict__ Vp)
{
    __shared__ __align__(16) bf16 t[64][80];
    int h = blockIdx.y, s0 = blockIdx.x * 64;
    int tid = threadIdx.x;
    for (int i = tid; i < 64 * 9; i += 256) {
        int sl = i / 9, c8 = (i % 9) * 8;
        *(bf16x8*)&t[sl][c8] =
            *(const bf16x8*)&qkv[(size_t)(s0 + sl) * N3 + 2 * HID + h * HD + c8];
    }
    __syncthreads();
    for (int i = tid; i < DV * 8; i += 256) {
        int d = i / 8, c = i % 8;                 // chunk c = keys 8c..8c+7 within 64-group
        bf16x8 v;
#pragma unroll
        for (int j = 0; j < 8; ++j)
            v[j] = (d < HD) ? t[c * 8 + j][d] : ((d == 72) ? (bf16)1.f : (bf16)0.f);
        int csw = c ^ (d & 7);                    // pre-swizzle within 64-key group
        *(bf16x8*)&Vp[((size_t)h * DVP + d) * SEQ + s0 + csw * 8] = v;
    }
}

// -------- flash attention: 8 waves x 32q, KVB=64 double-buffered, T3/T4 pipeline --------
// LDS per buf: K 64x256B = 16KB, V 128x128B = 16KB; 2 bufs = 64KB
__global__ __launch_bounds__(512, 2)
void attn_fwd4(const bf16* __restrict__ Qp, const bf16* __restrict__ Kp,
               const bf16* __restrict__ Vp, bf16* __restrict__ Oout)
{
    __shared__ __align__(16) char smem[65536];

    const int wgid = xcd_swz(blockIdx.y * gridDim.x + blockIdx.x, gridDim.x * gridDim.y);
    const int h  = wgid / (SEQ / QBLK);
    const int q0 = (wgid % (SEQ / QBLK)) * QBLK;
    const int tid = threadIdx.x, lane = tid & 63, w = tid >> 6;
    const int ql = lane & 31, hi = lane >> 5;
    const int q  = q0 + w * 32 + ql;

    bf16x8 qf[5];
    const bf16* qbase = Qp + ((size_t)h * SEQ + q) * DQ + hi * 8;
#pragma unroll
    for (int ks = 0; ks < 5; ++ks) qf[ks] = *(const bf16x8*)(qbase + ks * 16);

    f32x16 o[3] = {};            // O^T accum: col=q (lane-scalar), rows=d; row 72 carries l
    float m = -1e30f;            // log2 domain

    const bf16* ksrc = Kp + (size_t)h * SEQ * DK;
    const bf16* vsrc = Vp + (size_t)h * DVP * SEQ;

    // stage tile T (64 keys) into buffer B: 2048 chunks of 16B, 4 per thread
#define STAGE(T, B) do {                                                          \
        int base_ = (B) * 32768;                                                  \
        _Pragma("unroll")                                                         \
        for (int i_ = 0; i_ < 4; ++i_) {                                          \
            int c_ = i_ * 512 + tid;                                              \
            const bf16* g_;                                                       \
            if (i_ < 2) g_ = ksrc + (size_t)((T) * 64 + (c_ >> 4)) * DK + (c_ & 15) * 8; \
            else { int cv_ = c_ - 1024;                                           \
                   g_ = vsrc + (size_t)(cv_ >> 3) * SEQ + (T) * 64 + (cv_ & 7) * 8; } \
            gload_lds16(g_, smem + base_ + c_ * 16);                              \
        }                                                                         \
    } while (0)

    const int NT = SEQ / 64;
    STAGE(0, 0);
    asm volatile("s_waitcnt vmcnt(0)" ::: "memory");
    __builtin_amdgcn_s_barrier();

    for (int t = 0; t < NT; ++t) {
        int cur = t & 1;
        __builtin_amdgcn_sched_barrier(0);
        if (t + 1 < NT) STAGE(t + 1, cur ^ 1);

        const char* bK = smem + cur * 32768;
        const char* bV = bK + 16384;

        for (int kb = 0; kb < 2; ++kb) {
            // ---- S^T = mfma(K, Q) ----
            f32x16 s = {};
            int krow = kb * 32 + ql;
            int ksw  = krow & 15;
            const char* krp = bK + krow * 256;
            __builtin_amdgcn_s_setprio(1);
#pragma unroll
            for (int ks = 0; ks < 5; ++ks) {
                bf16x8 kf = *(const bf16x8*)(krp + (((ks * 2 + hi) ^ ksw) * 16));
                s = __builtin_amdgcn_mfma_f32_32x32x16_bf16(kf, qf[ks], s, 0, 0, 0);
            }
            __builtin_amdgcn_s_setprio(0);

            // ---- online softmax (lane-local row; partner lane^32 holds other 16 keys) ----
            float pmax = fmaxf(fmaxf(s[0], s[1]), s[2]);
#pragma unroll
            for (int r = 3; r < 16; r += 2) pmax = fmaxf(fmaxf(pmax, s[r]), s[r + 1]);
            pmax = fmaxf(pmax, __shfl_xor(pmax, 32));
            if (__any(pmax > m + 11.0f)) {        // defer-max (T13)
                float nm  = fmaxf(m, pmax);
                float fac = EXP2F(m - nm);
                m = nm;
#pragma unroll
                for (int db = 0; db < 3; ++db)
#pragma unroll
                    for (int r = 0; r < 16; ++r) o[db][r] *= fac;
            }
            uint32_t wd[8];
#pragma unroll
            for (int i = 0; i < 8; ++i) {
                uint16_t b0 = bfbits(EXP2F(s[2*i]   - m));
                uint16_t b1 = bfbits(EXP2F(s[2*i+1] - m));
                wd[i] = (uint32_t)b0 | ((uint32_t)b1 << 16);
            }

            // ---- build PV B-fragments in-register (halves exchange via lane^32) ----
            uint32_t r0 = __shfl_xor(hi ? wd[0] : wd[2], 32);
            uint32_t r1 = __shfl_xor(hi ? wd[1] : wd[3], 32);
            uint32_t r2 = __shfl_xor(hi ? wd[4] : wd[6], 32);
            uint32_t r3 = __shfl_xor(hi ? wd[5] : wd[7], 32);
            union { uint32_t u[4]; bf16x8 v; } pa0, pa1;
            pa0.u[0] = hi ? r0 : wd[0];  pa0.u[1] = hi ? r1 : wd[1];
            pa0.u[2] = hi ? wd[2] : r0;  pa0.u[3] = hi ? wd[3] : r1;
            pa1.u[0] = hi ? r2 : wd[4];  pa1.u[1] = hi ? r3 : wd[5];
            pa1.u[2] = hi ? wd[6] : r2;  pa1.u[3] = hi ? wd[7] : r3;

            // ---- O^T += mfma(V^T, P)  (V row 72 = ones -> accumulates l) ----
            __builtin_amdgcn_s_setprio(1);
#pragma unroll
            for (int db = 0; db < 3; ++db) {
                int vrow = db * 32 + ql;
                int vsw  = vrow & 7;
                const char* vrp = bV + vrow * 128;
                bf16x8 v0 = *(const bf16x8*)(vrp + (((kb * 4 + hi)     ^ vsw) * 16));
                o[db] = __builtin_amdgcn_mfma_f32_32x32x16_bf16(v0, pa0.v, o[db], 0, 0, 0);
                bf16x8 v1 = *(const bf16x8*)(vrp + (((kb * 4 + 2 + hi) ^ vsw) * 16));
                o[db] = __builtin_amdgcn_mfma_f32_32x32x16_bf16(v1, pa1.v, o[db], 0, 0, 0);
            }
            __builtin_amdgcn_s_setprio(0);
        }

        __builtin_amdgcn_sched_barrier(0);
        asm volatile("s_waitcnt vmcnt(0)" ::: "memory");   // drain stage(t+1)
        __builtin_amdgcn_s_barrier();                       // all waves done with buf[cur]
    }
#undef STAGE

    // ---- epilogue: LDS transpose (stride 82 = 41 words, odd -> conflict-free) ----
    __syncthreads();
    bf16* Os = (bf16*)smem;                        // [QBLK][82]
    {
        float lv  = o[2][4];                       // d=72 row holds l (hi=0 lanes)
        float lo_ = __shfl_xor(lv, 32);
        float invl = 1.0f / (hi ? lo_ : lv);
        int qloc = w * 32 + ql;
#pragma unroll
        for (int db = 0; db < 3; ++db) {
#pragma unroll
            for (int r = 0; r < 16; ++r) {
                int dloc = (r & 3) + 8 * (r >> 2) + 4 * hi;
                int d = db * 32 + dloc;
                if (d < HD) Os[qloc * 82 + d] = (bf16)(o[db][r] * invl);
            }
        }
    }
    __syncthreads();
    for (int i = tid; i < QBLK * 36; i += 512) {
        int row = i / 36, c = i % 36;
        uint32_t val = *(const uint32_t*)((const char*)Os + row * 164 + c * 4);
        *(uint32_t*)((char*)Oout + (size_t)(q0 + row) * 2304 + h * 144 + c * 4) = val;
    }
}

extern "C" void kernel_launch(void* const* d_in, const int* in_sizes, int n_in,
                              void* d_out, int out_size, void* d_ws, size_t ws_size,
                              hipStream_t stream)
{
    const float* hidden = (const float*)d_in[0];
    // d_in[1] = cu_seqlens: unused by the reference
    const float* cosT  = (const float*)d_in[2];
    const float* sinT  = (const float*)d_in[3];
    const float* Wqkv  = (const float*)d_in[4];
    const float* bqkv  = (const float*)d_in[5];
    const float* Wproj = (const float*)d_in[6];
    const float* bproj = (const float*)d_in[7];

    char* ws = (char*)d_ws;
    size_t off = 0;
    auto alloc = [&](size_t bytes) {
        char* p = ws + off;
        off += (bytes + 255) & ~(size_t)255;
        return p;
    };
    bf16* hid_b  = (bf16*)alloc((size_t)SEQ * HID * 2);
    bf16* WqkvT  = (bf16*)alloc((size_t)N3  * HID * 2);
    bf16* WprojT = (bf16*)alloc((size_t)HID * HID * 2);
    bf16* qkv_b  = (bf16*)alloc((size_t)SEQ * N3  * 2);
    bf16* Qp     = (bf16*)alloc((size_t)NH * SEQ * DQ * 2);
    bf16* Kp     = (bf16*)alloc((size_t)NH * SEQ * DK * 2);
    bf16* Vp     = (bf16*)alloc((size_t)NH * DVP * SEQ * 2);
    bf16* attno  = hid_b;  // overlay: hid_b dead after GEMM1

    cvt_bf16<<<SEQ * HID / (256 * 8), 256, 0, stream>>>(hidden, hid_b, SEQ * HID / 8);
    transpose_cvt<<<dim3(N3 / 32, HID / 32), 256, 0, stream>>>(Wqkv, WqkvT, HID, N3);
    transpose_cvt<<<dim3(HID / 32, HID / 32), 256, 0, stream>>>(Wproj, WprojT, HID, HID);
    gemm_bt<0><<<dim3(SEQ / 128, N3 / 128), 256, 0, stream>>>(hid_b, WqkvT, bqkv, qkv_b,
                                                              SEQ, N3, HID);
    rope_pack_qk2<<<NH * SEQ * 128 / 256, 256, 0, stream>>>(qkv_b, cosT, sinT, Qp, Kp);
    pack_v2<<<dim3(SEQ / 64, NH), 256, 0, stream>>>(qkv_b, Vp);
    attn_fwd4<<<dim3(SEQ / QBLK, NH), 512, 0, stream>>>(Qp, Kp, Vp, attno);
    gemm_bt<1><<<dim3(SEQ / 128, HID / 128), 256, 0, stream>>>(attno, WprojT, bproj, d_out,
                                                               SEQ, HID, HID);
}

// Round 6
// 239.674 us; speedup vs baseline: 1.7103x; 1.0365x over previous
//
#include <hip/hip_runtime.h>
#include <hip/hip_bf16.h>
#include <stdint.h>

#define SEQ 4096
#define HID 1152
#define NH  16
#define HD  72
#define N3  3456
#define DQ  80     // Q padded head dim (5 x 16)
#define QBLK 256   // q rows per block (8 waves x 32)

typedef __bf16 bf16;
typedef __bf16 bf16x8 __attribute__((ext_vector_type(8)));
typedef float  f32x4  __attribute__((ext_vector_type(4)));
typedef float  f32x16 __attribute__((ext_vector_type(16)));
typedef uint32_t u32x4 __attribute__((ext_vector_type(4)));

#define EXP2F(x) __builtin_amdgcn_exp2f(x)
#define PLSWAP(a, b) asm("v_permlane32_swap_b32 %0, %1" : "+v"(a), "+v"(b))

__device__ __forceinline__ void gload_lds16(const void* g, void* l) {
    __builtin_amdgcn_global_load_lds(
        (__attribute__((address_space(1))) void*)(void*)g,
        (__attribute__((address_space(3))) void*)l, 16, 0, 0);
}
__device__ __forceinline__ uint16_t bfbits(float x) {
    return __builtin_bit_cast(uint16_t, (bf16)x);
}

// bijective XCD swizzle (nwg % 8 == 0 for every launch below)
__device__ __forceinline__ int xcd_swz(int orig, int nwg) {
    return (orig & 7) * (nwg >> 3) + (orig >> 3);
}

// ---------------- elementwise f32 -> bf16 (8/thread) ----------------
__global__ void cvt_bf16(const float* __restrict__ in, bf16* __restrict__ out, int n8)
{
    int i = blockIdx.x * 256 + threadIdx.x;
    if (i >= n8) return;
    const float4* p = (const float4*)in + (size_t)i * 2;
    float4 a = p[0], b = p[1];
    bf16x8 o;
    o[0]=(bf16)a.x; o[1]=(bf16)a.y; o[2]=(bf16)a.z; o[3]=(bf16)a.w;
    o[4]=(bf16)b.x; o[5]=(bf16)b.y; o[6]=(bf16)b.z; o[7]=(bf16)b.w;
    ((bf16x8*)out)[i] = o;
}

// ---------------- [R][C] f32 -> [C][R] bf16 (tiled transpose) ----------------
__global__ void transpose_cvt(const float* __restrict__ in, bf16* __restrict__ out, int R, int C)
{
    __shared__ float tl[32][33];
    int c0 = blockIdx.x * 32, r0 = blockIdx.y * 32;
    int tx = threadIdx.x & 31, ty = threadIdx.x >> 5;
#pragma unroll
    for (int i = 0; i < 4; ++i)
        tl[ty + 8*i][tx] = in[(size_t)(r0 + ty + 8*i) * C + c0 + tx];
    __syncthreads();
#pragma unroll
    for (int i = 0; i < 4; ++i)
        out[(size_t)(c0 + ty + 8*i) * R + r0 + tx] = (bf16)tl[tx][ty + 8*i];
}

// ---------------- GEMM: C[M][N] = A[M][K] * BT[N][K]^T + bias ----------------
template<int OUT_F32>
__global__ __launch_bounds__(256)
void gemm_bt(const bf16* __restrict__ A, const bf16* __restrict__ BT,
             const float* __restrict__ bias, void* __restrict__ out,
             int M, int N, int K)
{
    __shared__ __align__(16) bf16 As[128 * 32];
    __shared__ __align__(16) bf16 Bs[128 * 32];
    int tid = threadIdx.x;
    int lane = tid & 63, w = tid >> 6;
    int wm = w & 1, wn = w >> 1;
    int nwg  = gridDim.x * gridDim.y;
    int wgid = xcd_swz(blockIdx.y * gridDim.x + blockIdx.x, nwg);
    int m0 = (wgid % gridDim.x) * 128, n0 = (wgid / gridDim.x) * 128;
    int lq = lane & 15, lk = lane >> 4;

    f32x4 acc[4][4] = {};

    for (int k0 = 0; k0 < K; k0 += 32) {
        __syncthreads();
#pragma unroll
        for (int i = 0; i < 2; ++i) {
            int c = w * 128 + i * 64 + lane;
            const bf16* ga = A  + (size_t)(m0 + (c >> 2)) * K + k0 + (c & 3) * 8;
            const bf16* gb = BT + (size_t)(n0 + (c >> 2)) * K + k0 + (c & 3) * 8;
            gload_lds16(ga, (char*)As + (w * 128 + i * 64) * 16);
            gload_lds16(gb, (char*)Bs + (w * 128 + i * 64) * 16);
        }
        __syncthreads();
        bf16x8 af[4], bfr[4];
#pragma unroll
        for (int m = 0; m < 4; ++m)
            af[m] = *(const bf16x8*)&As[(wm * 64 + m * 16 + lq) * 32 + lk * 8];
#pragma unroll
        for (int n = 0; n < 4; ++n)
            bfr[n] = *(const bf16x8*)&Bs[(wn * 64 + n * 16 + lq) * 32 + lk * 8];
#pragma unroll
        for (int m = 0; m < 4; ++m)
#pragma unroll
            for (int n = 0; n < 4; ++n)
                acc[m][n] = __builtin_amdgcn_mfma_f32_16x16x32_bf16(af[m], bfr[n], acc[m][n], 0, 0, 0);
    }

    int rb = m0 + wm * 64, cb = n0 + wn * 64;
#pragma unroll
    for (int m = 0; m < 4; ++m) {
#pragma unroll
        for (int n = 0; n < 4; ++n) {
            int col = cb + n * 16 + lq;
            float b = bias[col];
#pragma unroll
            for (int r = 0; r < 4; ++r) {
                int row = rb + m * 16 + lk * 4 + r;
                float v = acc[m][n][r] + b;
                if (OUT_F32) ((float*)out)[(size_t)row * N + col] = v;
                else         ((bf16*)out)[(size_t)row * N + col] = (bf16)v;
            }
        }
    }
}

// ---- RoPE + pack: Qp [h][s][80] (scale*log2e folded); K into KVp tile image ----
// KVp[h][t][16384 elem]: elems 0..8191 = K image (64 keys x 16 chunks, chunk
// swizzled = dchunk ^ (key&15)); elems 8192..16383 = V image.
__global__ void rope_pack_qk3(const bf16* __restrict__ qkv, const float* __restrict__ cs,
                              const float* __restrict__ sn, bf16* __restrict__ Qp,
                              bf16* __restrict__ KVp)
{
    int idx = blockIdx.x * 256 + threadIdx.x;    // NH*SEQ*128
    int dd = idx & 127;
    int s  = (idx >> 7) & (SEQ - 1);
    int h  = idx >> 19;
    float qv = 0.f, kv = 0.f;
    if (dd < HD) {
        const bf16* row = qkv + (size_t)s * N3 + h * HD;
        float c  = cs[s * HD + dd], si = sn[s * HD + dd];
        int   dp = (dd < 36) ? dd + 36 : dd - 36;
        float sg = (dd < 36) ? -1.f : 1.f;
        float qa = (float)row[dd],       qb = (float)row[dp];
        float ka = (float)row[HID + dd], kb = (float)row[HID + dp];
        qv = (qa * c + sg * qb * si) * (0.11785113019775793f * 1.4426950408889634f);
        kv =  ka * c + sg * kb * si;
    }
    int t = s >> 6, key = s & 63;
    int chunk = key * 16 + ((dd >> 3) ^ (key & 15));
    KVp[((size_t)(h * 64 + t)) * 16384 + chunk * 8 + (dd & 7)] = (bf16)kv;
    if (dd < DQ) Qp[((size_t)h * SEQ + s) * DQ + dd] = (bf16)qv;
}

// ---- pack V into KVp tile image: chunk (d*8+cpos) holds keys (cpos^(d&7))*8.. at dim d ----
// d 0..71 = data; d 72 = ones (l via MFMA); d 73..127 = zero
__global__ void pack_v3(const bf16* __restrict__ qkv, bf16* __restrict__ KVp)
{
    __shared__ __align__(16) bf16 tl[64][80];
    int h = blockIdx.y, t = blockIdx.x, s0 = t * 64;
    int tid = threadIdx.x;
    for (int i = tid; i < 64 * 9; i += 256) {
        int key = i / 9, c8 = (i % 9) * 8;
        *(bf16x8*)&tl[key][c8] =
            *(const bf16x8*)&qkv[(size_t)(s0 + key) * N3 + 2 * HID + h * HD + c8];
    }
    __syncthreads();
    bf16* dst = KVp + ((size_t)(h * 64 + t)) * 16384 + 8192;
    for (int vcid = tid; vcid < 1024; vcid += 256) {
        int d = vcid >> 3, cpos = vcid & 7;
        int kb8 = (cpos ^ (d & 7)) << 3;
        bf16x8 v;
#pragma unroll
        for (int j = 0; j < 8; ++j)
            v[j] = (d < HD) ? tl[kb8 + j][d] : ((d == HD) ? (bf16)1.f : (bf16)0.f);
        *(bf16x8*)&dst[vcid * 8] = v;
    }
}

// -------- flash attention: 8 waves x 32q, 64-key tiles double-buffered --------
// All LDS-read addresses precomputed per-lane (swizzle is ql-invariant); loop
// unrolled x2 so buffer offsets are immediates. P-fragments via permlane32_swap.
__global__ __launch_bounds__(512, 2)
void attn_fwd5(const bf16* __restrict__ Qp, const bf16* __restrict__ KVp,
               bf16* __restrict__ Oout)
{
    __shared__ __align__(16) char smem[65536];

    const int wgid = xcd_swz(blockIdx.x, gridDim.x);
    const int h  = wgid >> 4;
    const int q0 = (wgid & 15) * QBLK;
    const int tid = threadIdx.x, lane = tid & 63, w = tid >> 6;
    const int ql = lane & 31, hi = lane >> 5;
    const int q  = q0 + w * 32 + ql;

    // Q fragments (B-operand): Qf[ks][j] = Q[q][ks*16 + hi*8 + j]
    bf16x8 qf[5];
    const bf16* qbase = Qp + ((size_t)h * SEQ + q) * DQ + hi * 8;
#pragma unroll
    for (int ks = 0; ks < 5; ++ks) qf[ks] = *(const bf16x8*)(qbase + ks * 16);

    // precomputed swizzled LDS byte-offsets (lane-invariant across tiles/kb)
    int aK[5], aV[4];
#pragma unroll
    for (int ks = 0; ks < 5; ++ks)
        aK[ks] = ql * 256 + (((ks * 2 + hi) ^ (ql & 15)) * 16);
#pragma unroll
    for (int u = 0; u < 4; ++u)
        aV[u] = 16384 + ql * 128 + (((u * 2 + hi) ^ (ql & 7)) * 16);

    f32x16 o[3] = {};            // O^T accum: col=q (lane-scalar), rows=d; row 72 = l
    float m = -1e30f;            // log2 domain

    const bf16* kvbase = KVp + (size_t)h * (64 * 16384) + tid * 8;
    const int NT = 64;

    // prologue: stage tile 0 into buf 0
#pragma unroll
    for (int i = 0; i < 4; ++i)
        gload_lds16(kvbase + i * 4096, smem + tid * 16 + i * 8192);
    asm volatile("s_waitcnt vmcnt(0)" ::: "memory");
    __builtin_amdgcn_s_barrier();

    auto body = [&](auto cc, int T) {
        constexpr int CUR = decltype(cc)::v;
        __builtin_amdgcn_sched_barrier(0);
        if (T + 1 < NT) {
#pragma unroll
            for (int i = 0; i < 4; ++i)
                gload_lds16(kvbase + (size_t)(T + 1) * 16384 + i * 4096,
                            smem + (CUR ^ 1) * 32768 + tid * 16 + i * 8192);
        }
        // ---- S^T for both 32-key halves (2 independent MFMA chains) ----
        f32x16 sa = {}, sb = {};
        __builtin_amdgcn_s_setprio(1);
#pragma unroll
        for (int ks = 0; ks < 5; ++ks) {
            bf16x8 kf = *(const bf16x8*)(smem + CUR * 32768 + aK[ks]);
            sa = __builtin_amdgcn_mfma_f32_32x32x16_bf16(kf, qf[ks], sa, 0, 0, 0);
        }
#pragma unroll
        for (int ks = 0; ks < 5; ++ks) {
            bf16x8 kf = *(const bf16x8*)(smem + CUR * 32768 + 8192 + aK[ks]);
            sb = __builtin_amdgcn_mfma_f32_32x32x16_bf16(kf, qf[ks], sb, 0, 0, 0);
        }
        __builtin_amdgcn_s_setprio(0);

        // ---- joint online softmax over 64 keys (max3-shaped tree) ----
        float x0 = fmaxf(fmaxf(sa[0], sa[1]), sa[2]);
        float x1 = fmaxf(fmaxf(sa[3], sa[4]), sa[5]);
        float x2 = fmaxf(fmaxf(sa[6], sa[7]), sa[8]);
        float x3 = fmaxf(fmaxf(sa[9], sa[10]), sa[11]);
        float x4 = fmaxf(fmaxf(sa[12], sa[13]), sa[14]);
        float x5 = fmaxf(fmaxf(sa[15], sb[0]), sb[1]);
        float x6 = fmaxf(fmaxf(sb[2], sb[3]), sb[4]);
        float x7 = fmaxf(fmaxf(sb[5], sb[6]), sb[7]);
        float x8 = fmaxf(fmaxf(sb[8], sb[9]), sb[10]);
        float x9 = fmaxf(fmaxf(sb[11], sb[12]), sb[13]);
        float xa = fmaxf(sb[14], sb[15]);
        float y0 = fmaxf(fmaxf(x0, x1), x2);
        float y1 = fmaxf(fmaxf(x3, x4), x5);
        float y2 = fmaxf(fmaxf(x6, x7), x8);
        float y3 = fmaxf(x9, xa);
        float pmax = fmaxf(fmaxf(y0, y1), fmaxf(y2, y3));
        pmax = fmaxf(pmax, __shfl_xor(pmax, 32));
        if (__any(pmax > m + 11.0f)) {           // defer-max (T13)
            float nm  = fmaxf(m, pmax);
            float fac = EXP2F(m - nm);
            m = nm;
#pragma unroll
            for (int db = 0; db < 3; ++db)
#pragma unroll
                for (int r = 0; r < 16; ++r) o[db][r] *= fac;
        }
        uint32_t wd[16];
#pragma unroll
        for (int i = 0; i < 8; ++i) {
            uint16_t b0 = bfbits(EXP2F(sa[2 * i]     - m));
            uint16_t b1 = bfbits(EXP2F(sa[2 * i + 1] - m));
            wd[i] = (uint32_t)b0 | ((uint32_t)b1 << 16);
        }
#pragma unroll
        for (int i = 0; i < 8; ++i) {
            uint16_t b0 = bfbits(EXP2F(sb[2 * i]     - m));
            uint16_t b1 = bfbits(EXP2F(sb[2 * i + 1] - m));
            wd[8 + i] = (uint32_t)b0 | ((uint32_t)b1 << 16);
        }

        // ---- P fragments: key-halves exchange via permlane32_swap ----
        PLSWAP(wd[0], wd[2]);   PLSWAP(wd[1], wd[3]);
        PLSWAP(wd[4], wd[6]);   PLSWAP(wd[5], wd[7]);
        PLSWAP(wd[8], wd[10]);  PLSWAP(wd[9], wd[11]);
        PLSWAP(wd[12], wd[14]); PLSWAP(wd[13], wd[15]);
        u32x4 w0 = {wd[0], wd[1], wd[2], wd[3]};
        u32x4 w1 = {wd[4], wd[5], wd[6], wd[7]};
        u32x4 w2 = {wd[8], wd[9], wd[10], wd[11]};
        u32x4 w3 = {wd[12], wd[13], wd[14], wd[15]};
        bf16x8 pb0 = __builtin_bit_cast(bf16x8, w0);
        bf16x8 pb1 = __builtin_bit_cast(bf16x8, w1);
        bf16x8 pb2 = __builtin_bit_cast(bf16x8, w2);
        bf16x8 pb3 = __builtin_bit_cast(bf16x8, w3);

        // ---- O^T += mfma(V^T, P)  (V row 72 = ones -> accumulates l) ----
        __builtin_amdgcn_s_setprio(1);
#pragma unroll
        for (int db = 0; db < 3; ++db) {
            bf16x8 v0 = *(const bf16x8*)(smem + CUR * 32768 + db * 4096 + aV[0]);
            o[db] = __builtin_amdgcn_mfma_f32_32x32x16_bf16(v0, pb0, o[db], 0, 0, 0);
            bf16x8 v1 = *(const bf16x8*)(smem + CUR * 32768 + db * 4096 + aV[1]);
            o[db] = __builtin_amdgcn_mfma_f32_32x32x16_bf16(v1, pb1, o[db], 0, 0, 0);
            bf16x8 v2 = *(const bf16x8*)(smem + CUR * 32768 + db * 4096 + aV[2]);
            o[db] = __builtin_amdgcn_mfma_f32_32x32x16_bf16(v2, pb2, o[db], 0, 0, 0);
            bf16x8 v3 = *(const bf16x8*)(smem + CUR * 32768 + db * 4096 + aV[3]);
            o[db] = __builtin_amdgcn_mfma_f32_32x32x16_bf16(v3, pb3, o[db], 0, 0, 0);
        }
        __builtin_amdgcn_s_setprio(0);

        __builtin_amdgcn_sched_barrier(0);
        asm volatile("s_waitcnt vmcnt(0)" ::: "memory");   // own staged loads landed
        __builtin_amdgcn_s_barrier();                      // buf[CUR] fully consumed
    };

    struct C0 { enum { v = 0 }; };
    struct C1 { enum { v = 1 }; };
    for (int t = 0; t < NT; t += 2) {
        body(C0{}, t);
        body(C1{}, t + 1);
    }

    // ---- epilogue: LDS transpose (stride 82 = 41 words, odd -> conflict-free) ----
    __syncthreads();
    bf16* Os = (bf16*)smem;                        // [QBLK][82]
    {
        float lv  = o[2][4];                       // d=72 row holds l (hi=0 lanes)
        float lo_ = __shfl_xor(lv, 32);
        float invl = 1.0f / (hi ? lo_ : lv);
        int qloc = w * 32 + ql;
#pragma unroll
        for (int db = 0; db < 3; ++db) {
#pragma unroll
            for (int r = 0; r < 16; ++r) {
                int dloc = (r & 3) + 8 * (r >> 2) + 4 * hi;
                int d = db * 32 + dloc;
                if (d < HD) Os[qloc * 82 + d] = (bf16)(o[db][r] * invl);
            }
        }
    }
    __syncthreads();
    for (int i = tid; i < QBLK * 36; i += 512) {
        int row = i / 36, c = i % 36;
        uint32_t val = *(const uint32_t*)((const char*)Os + row * 164 + c * 4);
        *(uint32_t*)((char*)Oout + (size_t)(q0 + row) * 2304 + h * 144 + c * 4) = val;
    }
}

extern "C" void kernel_launch(void* const* d_in, const int* in_sizes, int n_in,
                              void* d_out, int out_size, void* d_ws, size_t ws_size,
                              hipStream_t stream)
{
    const float* hidden = (const float*)d_in[0];
    // d_in[1] = cu_seqlens: unused by the reference
    const float* cosT  = (const float*)d_in[2];
    const float* sinT  = (const float*)d_in[3];
    const float* Wqkv  = (const float*)d_in[4];
    const float* bqkv  = (const float*)d_in[5];
    const float* Wproj = (const float*)d_in[6];
    const float* bproj = (const float*)d_in[7];

    char* ws = (char*)d_ws;
    size_t off = 0;
    auto alloc = [&](size_t bytes) {
        char* p = ws + off;
        off += (bytes + 255) & ~(size_t)255;
        return p;
    };
    bf16* hid_b  = (bf16*)alloc((size_t)SEQ * HID * 2);
    bf16* WqkvT  = (bf16*)alloc((size_t)N3  * HID * 2);
    bf16* WprojT = (bf16*)alloc((size_t)HID * HID * 2);
    bf16* qkv_b  = (bf16*)alloc((size_t)SEQ * N3  * 2);
    bf16* Qp     = (bf16*)alloc((size_t)NH * SEQ * DQ * 2);
    bf16* KVp    = (bf16*)alloc((size_t)NH * 64 * 16384 * 2);
    bf16* attno  = hid_b;  // overlay: hid_b dead after GEMM1

    cvt_bf16<<<SEQ * HID / (256 * 8), 256, 0, stream>>>(hidden, hid_b, SEQ * HID / 8);
    transpose_cvt<<<dim3(N3 / 32, HID / 32), 256, 0, stream>>>(Wqkv, WqkvT, HID, N3);
    transpose_cvt<<<dim3(HID / 32, HID / 32), 256, 0, stream>>>(Wproj, WprojT, HID, HID);
    gemm_bt<0><<<dim3(SEQ / 128, N3 / 128), 256, 0, stream>>>(hid_b, WqkvT, bqkv, qkv_b,
                                                              SEQ, N3, HID);
    rope_pack_qk3<<<NH * SEQ * 128 / 256, 256, 0, stream>>>(qkv_b, cosT, sinT, Qp, KVp);
    pack_v3<<<dim3(SEQ / 64, NH), 256, 0, stream>>>(qkv_b, KVp);
    attn_fwd5<<<dim3(SEQ / QBLK * NH), 512, 0, stream>>>(Qp, KVp, attno);
    gemm_bt<1><<<dim3(SEQ / 128, HID / 128), 256, 0, stream>>>(attno, WprojT, bproj, d_out,
                                                               SEQ, HID, HID);
}